// Round 9
// baseline (2063.806 us; speedup 1.0000x reference)
//
#include <hip/hip_runtime.h>
#include <math.h>

// DualEncoder: two LSTMs (B=64,T=160,E=512,H=1024) + bilinear sigmoid.
// mode 2: cvt -> pre_gemm2 (X = emb@Wih^T + bias, all t) -> ONE persistent
//         kernel (64 blocks x 512 thr, round-7 step body): Whh in registers,
//         A staged to LDS coherently, 2-level padded flag barrier
//         (per-block arrival lines + leader-published go word).
// mode 1/0: fallback paths for smaller workspace.

#define BB 64
#define TT 160
#define EE 512
#define HH 1024
#define G4 4096
#define ROWS 128
#define NBLK 64         // persistent grid (2 chains x 32 col-blocks)

typedef unsigned short u16;
typedef unsigned int u32;
typedef __attribute__((ext_vector_type(8))) __bf16 bf16x8;
typedef __attribute__((ext_vector_type(8))) short short8;
typedef __attribute__((ext_vector_type(4))) short short4v;
typedef __attribute__((ext_vector_type(4))) float f32x4;
typedef __attribute__((ext_vector_type(2))) u32 u32x2;

__device__ __forceinline__ u16 f2b(float f) {          // f32 -> bf16 RNE
    unsigned u = __float_as_uint(f);
    u = u + 0x7fffu + ((u >> 16) & 1u);
    return (u16)(u >> 16);
}
__device__ __forceinline__ float b2f(u16 s) { return __uint_as_float(((unsigned)s) << 16); }

__device__ __forceinline__ f32x4 mfma16(short8 a, short8 b, f32x4 c) {
    return __builtin_amdgcn_mfma_f32_16x16x32_bf16(
        __builtin_bit_cast(bf16x8, a), __builtin_bit_cast(bf16x8, b), c, 0, 0, 0);
}

__device__ __forceinline__ void g2l16(const void* gsrc, void* ldst) {
    __builtin_amdgcn_global_load_lds(
        (const __attribute__((address_space(1))) u32*)gsrc,
        (__attribute__((address_space(3))) u32*)ldst, 16, 0, 0);
}
// device-coherent variant: cpol = sc0|sc1
__device__ __forceinline__ void g2l16c(const void* gsrc, void* ldst) {
    __builtin_amdgcn_global_load_lds(
        (const __attribute__((address_space(1))) u32*)gsrc,
        (__attribute__((address_space(3))) u32*)ldst, 16, 0, 17);
}

// ---------------- f32 -> bf16 bulk convert ----------------
__global__ __launch_bounds__(256) void cvt_kernel(const float* __restrict__ in,
                                                  u16* __restrict__ out, int n4) {
    int i = blockIdx.x * 256 + threadIdx.x;
    if (i < n4) {
        f32x4 v = *(const f32x4*)(in + (size_t)i * 4);
        short4v o;
        o.x = (short)f2b(v.x); o.y = (short)f2b(v.y);
        o.z = (short)f2b(v.z); o.w = (short)f2b(v.w);
        *(short4v*)(out + (size_t)i * 4) = o;
    }
}

// ---------------- X precompute (verified rounds 3-7) ----------------
__global__ __launch_bounds__(256) void pre_gemm2(
    const int* __restrict__ ctx, const int* __restrict__ rsp,
    const u16* __restrict__ embb, const u16* __restrict__ Wihb,
    const float* __restrict__ bih, const float* __restrict__ bhh,
    u16* __restrict__ xg)
{
    __shared__ __align__(16) u16 As[2][128][64];
    __shared__ __align__(16) u16 Ws[2][128][64];
    __shared__ int toks[128];
    const int tid = threadIdx.x;
    const int n0 = blockIdx.x * 128;
    const int t  = blockIdx.y;

    if (tid < 128) {
        int r = tid;
        toks[tid] = (r < BB) ? ctx[r * TT + t] : rsp[(r - BB) * TT + t];
    }
    __syncthreads();

    const u16* asrc[4]; const u16* bsrc[4];
    #pragma unroll
    for (int q = 0; q < 4; ++q) {
        int i = tid + q * 256;
        int row = i >> 3, c16 = i & 7;
        int scol = ((c16 ^ (row & 7)) * 8);
        asrc[q] = embb + (size_t)toks[row] * EE + scol;
        bsrc[q] = Wihb + (size_t)(n0 + row) * EE + scol;
    }

    const int lane = tid & 63, wave = tid >> 6;
    const int wr = (wave >> 1) * 64, wc = (wave & 1) * 64;
    const int l15 = lane & 15, l4 = lane >> 4;
    f32x4 acc[4][4] = {};

    #pragma unroll
    for (int q = 0; q < 4; ++q) {
        g2l16(asrc[q], (char*)&As[0][0][0] + (tid + q * 256) * 16);
        g2l16(bsrc[q], (char*)&Ws[0][0][0] + (tid + q * 256) * 16);
    }
    for (int it = 0; it < 8; ++it) {
        __syncthreads();
        if (it + 1 < 8) {
            int kk = (it + 1) * 64, bs = (it + 1) & 1;
            #pragma unroll
            for (int q = 0; q < 4; ++q) {
                g2l16(asrc[q] + kk, (char*)&As[bs][0][0] + (tid + q * 256) * 16);
                g2l16(bsrc[q] + kk, (char*)&Ws[bs][0][0] + (tid + q * 256) * 16);
            }
        }
        const int b = it & 1;
        #pragma unroll
        for (int ks = 0; ks < 2; ++ks) {
            int c16 = ks * 4 + l4;
            short8 a[4], w[4];
            #pragma unroll
            for (int mf = 0; mf < 4; ++mf) {
                int R = wr + mf * 16 + l15;
                a[mf] = *(const short8*)((const char*)&As[b][0][0] + R * 128 + ((c16 ^ (R & 7)) << 4));
            }
            #pragma unroll
            for (int nf = 0; nf < 4; ++nf) {
                int Nn = wc + nf * 16 + l15;
                w[nf] = *(const short8*)((const char*)&Ws[b][0][0] + Nn * 128 + ((c16 ^ (Nn & 7)) << 4));
            }
            #pragma unroll
            for (int mf = 0; mf < 4; ++mf)
                #pragma unroll
                for (int nf = 0; nf < 4; ++nf)
                    acc[mf][nf] = mfma16(a[mf], w[nf], acc[mf][nf]);
        }
    }

    u16* xp = xg + (size_t)t * ROWS * G4;
    #pragma unroll
    for (int nf = 0; nf < 4; ++nf) {
        int n = n0 + wc + nf * 16 + l15;
        float bias = bih[n] + bhh[n];
        #pragma unroll
        for (int mf = 0; mf < 4; ++mf)
            #pragma unroll
            for (int q = 0; q < 4; ++q) {
                int r = wr + mf * 16 + l4 * 4 + q;
                xp[(size_t)r * G4 + n] = f2b(acc[mf][nf][q] + bias);
            }
    }
}

// ---------------- persistent recurrent kernel v6 ----------------
// 64 blocks x 512 threads (2 chains x 32 col-blocks). Step body = round 7
// (verified): Whh 128 cols x 1024 K in registers, A staged to LDS in two
// K-halves via coherent global_load_lds (swizzled src), K-combine in LDS,
// 4 cells/thread in registers. NEW: 2-level padded flag barrier.
// barr layout per chain (u32 units): arrival[cg] at cg*32 (128B lines),
// go word at 1024. Chain c base = barr + c*2048.
__global__ __launch_bounds__(512, 2) void lstm_persist6(
    const u16* __restrict__ Whhb, const u16* __restrict__ xg,
    u16* __restrict__ hbuf, u32* __restrict__ barr)
{
    __shared__ __align__(16) u16 Abuf[64][512];      // 64 KB (one K-half)
    __shared__ __align__(16) float G[2][64][132];    // 66 KB

    const int tid = threadIdx.x;
    const int bx = blockIdx.x;
    const int cg = bx & 31, rg = bx >> 5;
    const int r0 = rg * 64, j0 = cg * 32;
    const int lane = tid & 63, w = tid >> 6;
    const int colt = w >> 2, q = w & 3;
    const int l15 = lane & 15, l4 = lane >> 4;

    // ---- Whh fragments -> registers (once; plain cached loads) ----
    short8 breg[4][8];
    #pragma unroll
    for (int nt = 0; nt < 4; ++nt) {
        int n = (colt * 2 + (nt >> 1)) * 1024 + j0 + (nt & 1) * 16 + l15;
        const u16* wp = Whhb + (size_t)n * HH + l4 * 8;
        #pragma unroll
        for (int z = 0; z < 8; ++z) {
            int kc = (z < 4) ? (q * 4 + z) : (16 + q * 4 + (z - 4));
            breg[nt][z] = *(const short8*)(wp + kc * 32);
        }
    }

    const int urow = tid >> 3;            // 0..63 local row
    const int jj4  = (tid & 7) * 4;       // 0..28 local h-col base
    float cst[4] = {0.f, 0.f, 0.f, 0.f};

    u32* const cbase = barr + (size_t)rg * 2048;   // my chain's barrier base

    __syncthreads();

    for (int t = 0; t < TT; ++t) {
        const u16* hin = hbuf + (size_t)(t & 1) * ROWS * HH;
        u16* hout      = hbuf + (size_t)((t + 1) & 1) * ROWS * HH;

        // ---- stage K-half 0 (coherent; swizzled src, linear LDS dest) ----
        #pragma unroll
        for (int j = 0; j < 8; ++j) {
            int row = w * 8 + j;
            g2l16c(hin + (size_t)(r0 + row) * HH + ((lane ^ j) * 8), &Abuf[row][0]);
        }
        // ---- xg prefetch (plain cached; consumed at cell update) ----
        u32x2 xv[4];
        {
            const u16* xp = xg + ((size_t)t * ROWS + r0 + urow) * G4 + j0 + jj4;
            #pragma unroll
            for (int g = 0; g < 4; ++g)
                asm volatile("global_load_dwordx2 %0, %1, off"
                             : "=v"(xv[g]) : "v"(xp + g * HH));
        }

        f32x4 acc[4][4] = {};

        // ---- half 0: wait A (xg still in flight), compute ----
        asm volatile("s_waitcnt vmcnt(4)" ::: "memory");
        __builtin_amdgcn_sched_barrier(0);
        __builtin_amdgcn_s_barrier();
        __builtin_amdgcn_sched_barrier(0);
        #pragma unroll
        for (int z4 = 0; z4 < 4; ++z4) {
            const int kcl = q * 4 + z4;
            short8 a[4];
            #pragma unroll
            for (int rt = 0; rt < 4; ++rt) {
                int row = rt * 16 + l15;
                int c16 = kcl * 4 + l4;
                a[rt] = *(const short8*)((const char*)&Abuf[0][0] +
                         row * 1024 + ((c16 ^ (l15 & 7)) << 4));
            }
            #pragma unroll
            for (int rt = 0; rt < 4; ++rt)
                #pragma unroll
                for (int nt = 0; nt < 4; ++nt)
                    acc[rt][nt] = mfma16(a[rt], breg[nt][z4], acc[rt][nt]);
        }
        asm volatile("s_waitcnt lgkmcnt(0)" ::: "memory");
        __builtin_amdgcn_s_barrier();
        __builtin_amdgcn_sched_barrier(0);

        // ---- stage K-half 1 (Abuf now free), wait, compute ----
        #pragma unroll
        for (int j = 0; j < 8; ++j) {
            int row = w * 8 + j;
            g2l16c(hin + (size_t)(r0 + row) * HH + 512 + ((lane ^ j) * 8), &Abuf[row][0]);
        }
        asm volatile("s_waitcnt vmcnt(0)" ::: "memory");   // A half1 + xg done
        __builtin_amdgcn_sched_barrier(0);
        __builtin_amdgcn_s_barrier();
        __builtin_amdgcn_sched_barrier(0);
        #pragma unroll
        for (int z4 = 0; z4 < 4; ++z4) {
            const int kcl = q * 4 + z4;
            short8 a[4];
            #pragma unroll
            for (int rt = 0; rt < 4; ++rt) {
                int row = rt * 16 + l15;
                int c16 = kcl * 4 + l4;
                a[rt] = *(const short8*)((const char*)&Abuf[0][0] +
                         row * 1024 + ((c16 ^ (l15 & 7)) << 4));
            }
            #pragma unroll
            for (int rt = 0; rt < 4; ++rt)
                #pragma unroll
                for (int nt = 0; nt < 4; ++nt)
                    acc[rt][nt] = mfma16(a[rt], breg[nt][4 + z4], acc[rt][nt]);
        }

        // ---- K-combine in LDS: q0/q1 store, q2/q3 add ----
        if (q < 2) {
            #pragma unroll
            for (int rt = 0; rt < 4; ++rt)
                #pragma unroll
                for (int nt = 0; nt < 4; ++nt) {
                    int col = colt * 64 + nt * 16 + l15;
                    int rowb = rt * 16 + l4 * 4;
                    #pragma unroll
                    for (int e = 0; e < 4; ++e)
                        G[q][rowb + e][col] = acc[rt][nt][e];
                }
        }
        asm volatile("s_waitcnt lgkmcnt(0)" ::: "memory");
        __builtin_amdgcn_s_barrier();
        __builtin_amdgcn_sched_barrier(0);
        if (q >= 2) {
            #pragma unroll
            for (int rt = 0; rt < 4; ++rt)
                #pragma unroll
                for (int nt = 0; nt < 4; ++nt) {
                    int col = colt * 64 + nt * 16 + l15;
                    int rowb = rt * 16 + l4 * 4;
                    #pragma unroll
                    for (int e = 0; e < 4; ++e)
                        G[q - 2][rowb + e][col] += acc[rt][nt][e];
                }
        }
        asm volatile("s_waitcnt lgkmcnt(0)" ::: "memory");
        __builtin_amdgcn_s_barrier();
        __builtin_amdgcn_sched_barrier(0);

        // ---- cell update: 4 cells/thread; coherent h store ----
        float gv[4][4];
        #pragma unroll
        for (int g = 0; g < 4; ++g) {
            f32x4 a0 = *(const f32x4*)&G[0][urow][g * 32 + jj4];
            f32x4 a1 = *(const f32x4*)&G[1][urow][g * 32 + jj4];
            gv[g][0] = a0.x + a1.x + b2f((u16)(xv[g].x & 0xffffu));
            gv[g][1] = a0.y + a1.y + b2f((u16)(xv[g].x >> 16));
            gv[g][2] = a0.z + a1.z + b2f((u16)(xv[g].y & 0xffffu));
            gv[g][3] = a0.w + a1.w + b2f((u16)(xv[g].y >> 16));
        }
        u16 hp[4];
        #pragma unroll
        for (int e = 0; e < 4; ++e) {
            float ii = 1.f / (1.f + expf(-gv[0][e]));
            float ff = 1.f / (1.f + expf(-gv[1][e]));
            float gg = tanhf(gv[2][e]);
            float oo = 1.f / (1.f + expf(-gv[3][e]));
            cst[e] = ff * cst[e] + ii * gg;
            hp[e] = f2b(oo * tanhf(cst[e]));
        }
        u32x2 hw;
        hw.x = (u32)hp[0] | ((u32)hp[1] << 16);
        hw.y = (u32)hp[2] | ((u32)hp[3] << 16);
        {
            u16* hpt = hout + (size_t)(r0 + urow) * HH + j0 + jj4;
            asm volatile("global_store_dwordx2 %0, %1, off sc0 sc1"
                         :: "v"(hpt), "v"(hw) : "memory");
        }

        // ---- 2-level padded flag barrier (per 32-block chain) ----
        if (t < TT - 1) {
            asm volatile("s_waitcnt vmcnt(0)" ::: "memory");  // my wave's h stores acked
            __builtin_amdgcn_s_barrier();                     // all waves drained
            __builtin_amdgcn_sched_barrier(0);
            const u32 target = (u32)(t + 1);
            if (tid == 0)                                     // arrival: own 128B line
                asm volatile("global_store_dword %0, %1, off sc0 sc1"
                             :: "v"(cbase + cg * 32), "v"(target) : "memory");
            if (w == 0) {
                if (cg == 0) {
                    // leader: lane-parallel poll of 32 arrival lines
                    const u32* ap = cbase + (lane & 31) * 32;
                    int spins = 0;
                    while (true) {
                        u32 v;
                        asm volatile("global_load_dword %0, %1, off sc0 sc1"
                                     : "=v"(v) : "v"(ap));
                        asm volatile("s_waitcnt vmcnt(0)" ::: "memory");
                        if (__all(v >= target)) break;
                        __builtin_amdgcn_s_sleep(1);
                        if (++spins > 8000000) break;   // safety bailout
                    }
                    if (lane == 0)                      // publish go word
                        asm volatile("global_store_dword %0, %1, off sc0 sc1"
                                     :: "v"(cbase + 1024), "v"(target) : "memory");
                } else {
                    // follower: poll the single go line (read-shared)
                    const u32* gp = cbase + 1024;
                    int spins = 0;
                    while (true) {
                        u32 v;
                        asm volatile("global_load_dword %0, %1, off sc0 sc1"
                                     : "=v"(v) : "v"(gp));
                        asm volatile("s_waitcnt vmcnt(0)" ::: "memory");
                        if (__all(v >= target)) break;
                        __builtin_amdgcn_s_sleep(1);
                        if (++spins > 8000000) break;   // safety bailout
                    }
                }
            }
            __builtin_amdgcn_s_barrier();
            __builtin_amdgcn_sched_barrier(0);
        }
    }
}

// ---------------- round-3 fallback: fused per-step kernel ----------------
template<int MODE>
__global__ __launch_bounds__(256) void step_fused(
    const int* __restrict__ ctx, const int* __restrict__ rsp,
    const u16* __restrict__ embb, const u16* __restrict__ Wihb,
    const u16* __restrict__ Whhb, const u16* __restrict__ xg,
    const float* __restrict__ bih, const float* __restrict__ bhh,
    const u16* __restrict__ hin, u16* __restrict__ hout,
    float* __restrict__ c_ws, int t)
{
    __shared__ __align__(16) u16 As[2][64][64];
    __shared__ __align__(16) u16 Ws[2][32][64];
    __shared__ float gs[64][32];
    __shared__ int toks[64];

    const int tid = threadIdx.x;
    const int cg = blockIdx.x & 127, rg = blockIdx.x >> 7;
    const int r0 = rg * 64, j0 = cg * 8;

    if (MODE == 1) {
        if (tid < 64) {
            int r = r0 + tid;
            toks[tid] = (r < BB) ? ctx[r * TT + t] : rsp[(r - BB) * TT + t];
        }
        __syncthreads();
    }

    const int arow0 = tid >> 3, c16a = tid & 7;
    const int arow1 = arow0 + 32;
    const int acol0 = ((c16a ^ (arow0 & 7)) * 8);
    const int acol1 = ((c16a ^ (arow1 & 7)) * 8);
    const u16* hA0 = hin + (size_t)(r0 + arow0) * HH + acol0;
    const u16* hA1 = hin + (size_t)(r0 + arow1) * HH + acol1;
    const u16* eA0 = nullptr; const u16* eA1 = nullptr;
    if (MODE == 1) {
        eA0 = embb + (size_t)toks[arow0] * EE + acol0;
        eA1 = embb + (size_t)toks[arow1] * EE + acol1;
    }
    const int nn = tid >> 3, c16b = tid & 7;
    const int bcol = ((c16b ^ (nn & 7)) * 8);
    const int wrow = (nn >> 3) * HH + j0 + (nn & 7);
    const u16* wHh = Whhb + (size_t)wrow * HH + bcol;
    const u16* wIh = (MODE == 1) ? (Wihb + (size_t)wrow * EE + bcol) : nullptr;

    const int NK = (MODE == 1) ? 24 : 16;

    auto stage = [&](int bs, int it) {
        int kk = it * 64;
        const u16 *s0, *s1, *sw;
        if (MODE == 1 && kk < EE) {
            s0 = eA0 + kk; s1 = eA1 + kk; sw = wIh + kk;
        } else {
            int khh = (MODE == 1) ? kk - EE : kk;
            s0 = hA0 + khh; s1 = hA1 + khh; sw = wHh + khh;
        }
        g2l16(s0, (char*)&As[bs][0][0] + tid * 16);
        g2l16(s1, (char*)&As[bs][0][0] + (tid + 256) * 16);
        g2l16(sw, (char*)&Ws[bs][0][0] + tid * 16);
    };

    const int lane = tid & 63, wave = tid >> 6;
    const int wr = wave * 16;
    const int l15 = lane & 15, l4 = lane >> 4;
    f32x4 acc[2] = {};

    stage(0, 0);
    for (int it = 0; it < NK; ++it) {
        __syncthreads();
        if (it + 1 < NK) stage((it + 1) & 1, it + 1);
        const int b = it & 1;
        #pragma unroll
        for (int ks = 0; ks < 2; ++ks) {
            int c16 = ks * 4 + l4;
            int R = wr + l15;
            short8 a = *(const short8*)((const char*)&As[b][0][0] + R * 128 + ((c16 ^ (R & 7)) << 4));
            #pragma unroll
            for (int nf = 0; nf < 2; ++nf) {
                int Nn = nf * 16 + l15;
                short8 w = *(const short8*)((const char*)&Ws[b][0][0] + Nn * 128 + ((c16 ^ (Nn & 7)) << 4));
                acc[nf] = mfma16(a, w, acc[nf]);
            }
        }
    }
    __syncthreads();
    #pragma unroll
    for (int nf = 0; nf < 2; ++nf)
        #pragma unroll
        for (int q = 0; q < 4; ++q)
            gs[wr + l4 * 4 + q][nf * 16 + l15] = acc[nf][q];
    __syncthreads();

    const int e = tid * 2;
    const int row = e >> 3, jj = e & 7;
    const int rglob = r0 + row;
    float g0[4], g1[4];
    #pragma unroll
    for (int g = 0; g < 4; ++g) { g0[g] = gs[row][g * 8 + jj]; g1[g] = gs[row][g * 8 + jj + 1]; }
    if (MODE == 2) {
        const u16* xp = xg + ((size_t)t * ROWS + rglob) * G4 + j0 + jj;
        #pragma unroll
        for (int g = 0; g < 4; ++g) { g0[g] += b2f(xp[g * HH]); g1[g] += b2f(xp[g * HH + 1]); }
    } else {
        #pragma unroll
        for (int g = 0; g < 4; ++g) {
            int n = g * HH + j0 + jj;
            g0[g] += bih[n] + bhh[n];
            g1[g] += bih[n + 1] + bhh[n + 1];
        }
    }
    size_t cidx = ((size_t)blockIdx.x * 64 + row) * 8 + jj;
    float c0 = c_ws[cidx], c1 = c_ws[cidx + 1];
    float i0 = 1.f / (1.f + expf(-g0[0])), i1 = 1.f / (1.f + expf(-g1[0]));
    float f0 = 1.f / (1.f + expf(-g0[1])), f1 = 1.f / (1.f + expf(-g1[1]));
    float t0 = tanhf(g0[2]),               t1 = tanhf(g1[2]);
    float o0 = 1.f / (1.f + expf(-g0[3])), o1 = 1.f / (1.f + expf(-g1[3]));
    float cn0 = f0 * c0 + i0 * t0;
    float cn1 = f1 * c1 + i1 * t1;
    c_ws[cidx] = cn0; c_ws[cidx + 1] = cn1;
    float h0 = o0 * tanhf(cn0), h1 = o1 * tanhf(cn1);
    unsigned hpk = (unsigned)f2b(h0) | ((unsigned)f2b(h1) << 16);
    *(unsigned*)(hout + (size_t)rglob * HH + j0 + jj) = hpk;
}

// ---------------- mode-0 fallback ----------------
__global__ __launch_bounds__(256) void step_gemm_f32(
    const int* __restrict__ ctx, const int* __restrict__ rsp,
    const float* __restrict__ emb, const float* __restrict__ Wih, const float* __restrict__ Whh,
    const u16* __restrict__ hb, float* __restrict__ gates, int t)
{
    __shared__ __align__(16) u16 As[64][32];
    __shared__ __align__(16) u16 Ws[64][32];
    __shared__ int toks[64];
    const int tid = threadIdx.x;
    const int n0 = blockIdx.x * 64;
    const int r0 = blockIdx.y * 64;
    const int part = blockIdx.z;
    if (tid < 64) {
        int r = r0 + tid;
        toks[tid] = (r < BB) ? ctx[r * TT + t] : rsp[(r - BB) * TT + t];
    }
    __syncthreads();
    const int lane = tid & 63, wave = tid >> 6;
    const int wr = (wave >> 1) * 32, wc = (wave & 1) * 32;
    const int l15 = lane & 15, l4 = lane >> 4;
    f32x4 acc[2][2] = {};
    const int kstart = part * 768;
    const int srow = tid >> 2;
    const int sseg = (tid & 3) * 8;
    for (int it = 0; it < 24; ++it) {
        const int kg = kstart + it * 32;
        const int kk = kg + sseg;
        if (kg < EE) {
            const float* s = emb + (size_t)toks[srow] * EE + kk;
            #pragma unroll
            for (int q = 0; q < 8; ++q) As[srow][sseg + q] = f2b(s[q]);
            const float* sw = Wih + (size_t)(n0 + srow) * EE + kk;
            #pragma unroll
            for (int q = 0; q < 8; ++q) Ws[srow][sseg + q] = f2b(sw[q]);
        } else {
            *(short8*)&As[srow][sseg] = *(const short8*)(hb + (size_t)(r0 + srow) * HH + (kk - EE));
            const float* sw = Whh + (size_t)(n0 + srow) * HH + (kk - EE);
            #pragma unroll
            for (int q = 0; q < 8; ++q) Ws[srow][sseg + q] = f2b(sw[q]);
        }
        __syncthreads();
        #pragma unroll
        for (int mf = 0; mf < 2; ++mf)
            #pragma unroll
            for (int nf = 0; nf < 2; ++nf)
                acc[mf][nf] = mfma16(*(const short8*)&As[wr + mf * 16 + l15][l4 * 8],
                                     *(const short8*)&Ws[wc + nf * 16 + l15][l4 * 8], acc[mf][nf]);
        __syncthreads();
    }
    float* gp = gates + (size_t)part * ROWS * G4;
    #pragma unroll
    for (int mf = 0; mf < 2; ++mf)
        #pragma unroll
        for (int nf = 0; nf < 2; ++nf)
            #pragma unroll
            for (int q = 0; q < 4; ++q) {
                int r = r0 + wr + mf * 16 + l4 * 4 + q;
                int n = n0 + wc + nf * 16 + l15;
                gp[(size_t)r * G4 + n] = acc[mf][nf][q];
            }
}

__global__ __launch_bounds__(256) void lstm_update0(
    const float* __restrict__ gates, const float* __restrict__ bih, const float* __restrict__ bhh,
    u16* __restrict__ hb, float* __restrict__ c)
{
    int idx = blockIdx.x * 256 + threadIdx.x;
    int r = idx >> 8;
    int jj = (idx & 255) * 4;
    const float* gp0 = gates + (size_t)r * G4;
    const float* gp1 = gates + (size_t)(ROWS + r) * G4;
    float gate[4][4];
    #pragma unroll
    for (int g = 0; g < 4; ++g) {
        int n = g * HH + jj;
        f32x4 a = *(const f32x4*)(gp0 + n);
        f32x4 b = *(const f32x4*)(gp1 + n);
        #pragma unroll
        for (int q = 0; q < 4; ++q) gate[g][q] = a[q] + b[q] + bih[n + q] + bhh[n + q];
    }
    int cidx = r * HH + jj;
    f32x4 cv = *(const f32x4*)(c + cidx);
    f32x4 cn; short4v hn;
    #pragma unroll
    for (int q = 0; q < 4; ++q) {
        float si = 1.f / (1.f + expf(-gate[0][q]));
        float sf = 1.f / (1.f + expf(-gate[1][q]));
        float tg = tanhf(gate[2][q]);
        float so = 1.f / (1.f + expf(-gate[3][q]));
        float cval = sf * cv[q] + si * tg;
        cn[q] = cval;
        ((short*)&hn)[q] = (short)f2b(so * tanhf(cval));
    }
    *(f32x4*)(c + cidx) = cn;
    *(short4v*)(hb + cidx) = hn;
}

// ---------------- bilinear head ----------------
__global__ __launch_bounds__(256) void bilinear(
    const u16* __restrict__ hb, const float* __restrict__ M, float* __restrict__ out)
{
    int b = blockIdx.x;
    __shared__ float chs[HH];
    __shared__ float red[256];
    const u16* ch = hb + (size_t)b * HH;
    const u16* rh = hb + (size_t)(BB + b) * HH;
    for (int i = threadIdx.x; i < HH; i += 256) chs[i] = b2f(ch[i]);
    __syncthreads();
    float vj[4] = {0.f, 0.f, 0.f, 0.f};
    for (int i = 0; i < HH; ++i) {
        float chi = chs[i];
        const float* Mr = M + (size_t)i * HH;
        #pragma unroll
        for (int q = 0; q < 4; ++q) vj[q] += chi * Mr[threadIdx.x + q * 256];
    }
    float acc = 0.f;
    #pragma unroll
    for (int q = 0; q < 4; ++q) acc += vj[q] * b2f(rh[threadIdx.x + q * 256]);
    red[threadIdx.x] = acc;
    __syncthreads();
    for (int s = 128; s > 0; s >>= 1) {
        if (threadIdx.x < s) red[threadIdx.x] += red[threadIdx.x + s];
        __syncthreads();
    }
    if (threadIdx.x == 0) out[b] = 1.0f / (1.0f + expf(-red[0]));
}

extern "C" void kernel_launch(void* const* d_in, const int* in_sizes, int n_in,
                              void* d_out, int out_size, void* d_ws, size_t ws_size,
                              hipStream_t stream) {
    const int*   ctx = (const int*)d_in[0];
    const int*   rsp = (const int*)d_in[1];
    const float* emb = (const float*)d_in[2];
    const float* Wih = (const float*)d_in[3];
    const float* Whh = (const float*)d_in[4];
    const float* bih = (const float*)d_in[5];
    const float* bhh = (const float*)d_in[6];
    const float* M   = (const float*)d_in[7];
    float* out = (float*)d_out;

    // workspace layout
    char* w = (char*)d_ws;
    u16*   hbuf  = (u16*)w;   w += (size_t)2 * ROWS * HH * 2;      // 512 KB
    float* c_ws  = (float*)w; w += (size_t)ROWS * HH * 4;          // 512 KB
    float* gates = (float*)w; w += (size_t)2 * ROWS * G4 * 4;      // 4 MB (mode 0)
    u16*   embb  = (u16*)w;   w += (size_t)32000 * EE * 2;         // 31.25 MB
    u16*   Wihb  = (u16*)w;   w += (size_t)G4 * EE * 2;            // 4 MB
    u16*   Whhb  = (u16*)w;   w += (size_t)G4 * HH * 2;            // 8 MB
    u32*   barr  = (u32*)w;   w += 16384;                          // padded barrier
    size_t conv_need = (size_t)(w - (char*)d_ws);
    u16*   xg    = (u16*)w;   w += (size_t)TT * ROWS * G4 * 2;     // 160 MB
    size_t xpre_need = (size_t)(w - (char*)d_ws);

    int mode = (ws_size >= xpre_need) ? 2 : (ws_size >= conv_need) ? 1 : 0;

    hipMemsetAsync(hbuf, 0, (size_t)2 * ROWS * HH * 2, stream);

    if (mode >= 1) {
        cvt_kernel<<<16000, 256, 0, stream>>>(emb, embb, 32000 * EE / 4);
        cvt_kernel<<<2048,  256, 0, stream>>>(Wih, Wihb, G4 * EE / 4);
        cvt_kernel<<<4096,  256, 0, stream>>>(Whh, Whhb, G4 * HH / 4);
    }

    if (mode == 2) {
        hipMemsetAsync(barr, 0, 16384, stream);
        pre_gemm2<<<dim3(G4 / 128, TT), 256, 0, stream>>>(ctx, rsp, embb, Wihb, bih, bhh, xg);
        lstm_persist6<<<NBLK, 512, 0, stream>>>(Whhb, xg, hbuf, barr);
        bilinear<<<BB, 256, 0, stream>>>(hbuf, M, out);   // final h in buffer 0
    } else if (mode == 1) {
        hipMemsetAsync(c_ws, 0, (size_t)ROWS * HH * 4, stream);
        for (int t = 0; t < TT; ++t) {
            const u16* hin = hbuf + (size_t)(t & 1) * ROWS * HH;
            u16* hout      = hbuf + (size_t)((t + 1) & 1) * ROWS * HH;
            step_fused<1><<<256, 256, 0, stream>>>(ctx, rsp, embb, Wihb, Whhb, xg,
                                                   bih, bhh, hin, hout, c_ws, t);
        }
        bilinear<<<BB, 256, 0, stream>>>(hbuf, M, out);
    } else {
        hipMemsetAsync(c_ws, 0, (size_t)ROWS * HH * 4, stream);
        u16* hb = hbuf;
        dim3 sg(G4 / 64, ROWS / 64, 2);
        for (int t = 0; t < TT; ++t) {
            step_gemm_f32<<<sg, 256, 0, stream>>>(ctx, rsp, emb, Wih, Whh, hb, gates, t);
            lstm_update0<<<128, 256, 0, stream>>>(gates, bih, bhh, hb, c_ws);
        }
        bilinear<<<BB, 256, 0, stream>>>(hb, M, out);
    }
}

// Round 10
// 1897.508 us; speedup vs baseline: 1.0876x; 1.0876x over previous
//
#include <hip/hip_runtime.h>
#include <math.h>

// DualEncoder: two LSTMs (B=64,T=160,E=512,H=1024) + bilinear sigmoid.
// mode 2: cvt -> pre_gemm2 (X = emb@Wih^T + bias, all t) -> ONE persistent
//         kernel (64 blocks x 512 thr): round-7 compute core; single-RTT
//         staging (both K-halves issued together), G-combine overlaid on
//         Abuf, flat padded arrival barrier (no leader/go hop), exp2 cell.
// mode 1/0: fallback paths for smaller workspace.

#define BB 64
#define TT 160
#define EE 512
#define HH 1024
#define G4 4096
#define ROWS 128
#define NBLK 64         // persistent grid (2 chains x 32 col-blocks)

typedef unsigned short u16;
typedef unsigned int u32;
typedef __attribute__((ext_vector_type(8))) __bf16 bf16x8;
typedef __attribute__((ext_vector_type(8))) short short8;
typedef __attribute__((ext_vector_type(4))) short short4v;
typedef __attribute__((ext_vector_type(4))) float f32x4;
typedef __attribute__((ext_vector_type(2))) u32 u32x2;

__device__ __forceinline__ u16 f2b(float f) {          // f32 -> bf16 RNE
    unsigned u = __float_as_uint(f);
    u = u + 0x7fffu + ((u >> 16) & 1u);
    return (u16)(u >> 16);
}
__device__ __forceinline__ float b2f(u16 s) { return __uint_as_float(((unsigned)s) << 16); }

// fast saturation-correct transcendentals (v_exp_f32 = 2^x, v_rcp_f32)
#define LOG2E 1.4426950408889634f
__device__ __forceinline__ float sigf(float x) {
    return __builtin_amdgcn_rcpf(1.f + __builtin_amdgcn_exp2f(-LOG2E * x));
}
__device__ __forceinline__ float tanhf_fast(float x) {
    // 1 - 2/(e^{2x}+1): x->+inf -> 1, x->-inf -> -1 (no inf/inf NaN)
    return 1.f - 2.f * __builtin_amdgcn_rcpf(1.f + __builtin_amdgcn_exp2f(2.f * LOG2E * x));
}

__device__ __forceinline__ f32x4 mfma16(short8 a, short8 b, f32x4 c) {
    return __builtin_amdgcn_mfma_f32_16x16x32_bf16(
        __builtin_bit_cast(bf16x8, a), __builtin_bit_cast(bf16x8, b), c, 0, 0, 0);
}

__device__ __forceinline__ void g2l16(const void* gsrc, void* ldst) {
    __builtin_amdgcn_global_load_lds(
        (const __attribute__((address_space(1))) u32*)gsrc,
        (__attribute__((address_space(3))) u32*)ldst, 16, 0, 0);
}
// device-coherent variant: cpol = sc0|sc1
__device__ __forceinline__ void g2l16c(const void* gsrc, void* ldst) {
    __builtin_amdgcn_global_load_lds(
        (const __attribute__((address_space(1))) u32*)gsrc,
        (__attribute__((address_space(3))) u32*)ldst, 16, 0, 17);
}

// ---------------- f32 -> bf16 bulk convert ----------------
__global__ __launch_bounds__(256) void cvt_kernel(const float* __restrict__ in,
                                                  u16* __restrict__ out, int n4) {
    int i = blockIdx.x * 256 + threadIdx.x;
    if (i < n4) {
        f32x4 v = *(const f32x4*)(in + (size_t)i * 4);
        short4v o;
        o.x = (short)f2b(v.x); o.y = (short)f2b(v.y);
        o.z = (short)f2b(v.z); o.w = (short)f2b(v.w);
        *(short4v*)(out + (size_t)i * 4) = o;
    }
}

// ---------------- X precompute (verified rounds 3-9) ----------------
__global__ __launch_bounds__(256) void pre_gemm2(
    const int* __restrict__ ctx, const int* __restrict__ rsp,
    const u16* __restrict__ embb, const u16* __restrict__ Wihb,
    const float* __restrict__ bih, const float* __restrict__ bhh,
    u16* __restrict__ xg)
{
    __shared__ __align__(16) u16 As[2][128][64];
    __shared__ __align__(16) u16 Ws[2][128][64];
    __shared__ int toks[128];
    const int tid = threadIdx.x;
    const int n0 = blockIdx.x * 128;
    const int t  = blockIdx.y;

    if (tid < 128) {
        int r = tid;
        toks[tid] = (r < BB) ? ctx[r * TT + t] : rsp[(r - BB) * TT + t];
    }
    __syncthreads();

    const u16* asrc[4]; const u16* bsrc[4];
    #pragma unroll
    for (int q = 0; q < 4; ++q) {
        int i = tid + q * 256;
        int row = i >> 3, c16 = i & 7;
        int scol = ((c16 ^ (row & 7)) * 8);
        asrc[q] = embb + (size_t)toks[row] * EE + scol;
        bsrc[q] = Wihb + (size_t)(n0 + row) * EE + scol;
    }

    const int lane = tid & 63, wave = tid >> 6;
    const int wr = (wave >> 1) * 64, wc = (wave & 1) * 64;
    const int l15 = lane & 15, l4 = lane >> 4;
    f32x4 acc[4][4] = {};

    #pragma unroll
    for (int q = 0; q < 4; ++q) {
        g2l16(asrc[q], (char*)&As[0][0][0] + (tid + q * 256) * 16);
        g2l16(bsrc[q], (char*)&Ws[0][0][0] + (tid + q * 256) * 16);
    }
    for (int it = 0; it < 8; ++it) {
        __syncthreads();
        if (it + 1 < 8) {
            int kk = (it + 1) * 64, bs = (it + 1) & 1;
            #pragma unroll
            for (int q = 0; q < 4; ++q) {
                g2l16(asrc[q] + kk, (char*)&As[bs][0][0] + (tid + q * 256) * 16);
                g2l16(bsrc[q] + kk, (char*)&Ws[bs][0][0] + (tid + q * 256) * 16);
            }
        }
        const int b = it & 1;
        #pragma unroll
        for (int ks = 0; ks < 2; ++ks) {
            int c16 = ks * 4 + l4;
            short8 a[4], w[4];
            #pragma unroll
            for (int mf = 0; mf < 4; ++mf) {
                int R = wr + mf * 16 + l15;
                a[mf] = *(const short8*)((const char*)&As[b][0][0] + R * 128 + ((c16 ^ (R & 7)) << 4));
            }
            #pragma unroll
            for (int nf = 0; nf < 4; ++nf) {
                int Nn = wc + nf * 16 + l15;
                w[nf] = *(const short8*)((const char*)&Ws[b][0][0] + Nn * 128 + ((c16 ^ (Nn & 7)) << 4));
            }
            #pragma unroll
            for (int mf = 0; mf < 4; ++mf)
                #pragma unroll
                for (int nf = 0; nf < 4; ++nf)
                    acc[mf][nf] = mfma16(a[mf], w[nf], acc[mf][nf]);
        }
    }

    u16* xp = xg + (size_t)t * ROWS * G4;
    #pragma unroll
    for (int nf = 0; nf < 4; ++nf) {
        int n = n0 + wc + nf * 16 + l15;
        float bias = bih[n] + bhh[n];
        #pragma unroll
        for (int mf = 0; mf < 4; ++mf)
            #pragma unroll
            for (int q = 0; q < 4; ++q) {
                int r = wr + mf * 16 + l4 * 4 + q;
                xp[(size_t)r * G4 + n] = f2b(acc[mf][nf][q] + bias);
            }
    }
}

// ---------------- persistent recurrent kernel v7 ----------------
// 64 blocks x 512 threads (2 chains x 32 col-blocks). Compute core = round 7
// (verified): Whh 128 cols x 1024 K in registers, 8 waves = colt(2) x q(4),
// K-combine. NEW: single-RTT staging (both halves at once into 128KB Abuf),
// G[2][64][132] f32 OVERLAID on Abuf (disjoint lifetime, barrier-separated),
// flat padded arrival-flag barrier (no leader), exp2 fast cell math.
__global__ __launch_bounds__(512, 2) void lstm_persist7(
    const u16* __restrict__ Whhb, const u16* __restrict__ xg,
    u16* __restrict__ hbuf, u32* __restrict__ barr)
{
    __shared__ __align__(16) u16 Abuf[2][64][512];   // 128 KB; G overlays post-MFMA

    const int tid = threadIdx.x;
    const int bx = blockIdx.x;
    const int cg = bx & 31, rg = bx >> 5;
    const int r0 = rg * 64, j0 = cg * 32;
    const int lane = tid & 63, w = tid >> 6;
    const int colt = w >> 2, q = w & 3;
    const int l15 = lane & 15, l4 = lane >> 4;

    float* const G = (float*)&Abuf[0][0][0];         // [2][64][132] overlay (67.6 KB)

    // ---- Whh fragments -> registers (once; plain cached loads) ----
    short8 breg[4][8];
    #pragma unroll
    for (int nt = 0; nt < 4; ++nt) {
        int n = (colt * 2 + (nt >> 1)) * 1024 + j0 + (nt & 1) * 16 + l15;
        const u16* wp = Whhb + (size_t)n * HH + l4 * 8;
        #pragma unroll
        for (int z = 0; z < 8; ++z) {
            int kc = (z < 4) ? (q * 4 + z) : (16 + q * 4 + (z - 4));
            breg[nt][z] = *(const short8*)(wp + kc * 32);
        }
    }

    const int urow = tid >> 3;            // 0..63 local row (cell ownership)
    const int jj4  = (tid & 7) * 4;       // 0..28 local h-col base
    float cst[4] = {0.f, 0.f, 0.f, 0.f};

    u32* const cb = barr + (size_t)rg * 2048;   // my chain's barrier base

    __syncthreads();

    for (int t = 0; t < TT; ++t) {
        const u16* hin = hbuf + (size_t)(t & 1) * ROWS * HH;
        u16* hout      = hbuf + (size_t)((t + 1) & 1) * ROWS * HH;

        // ---- stage BOTH K-halves at once (16 g2l16c; 1 LLC RTT) ----
        #pragma unroll
        for (int j = 0; j < 8; ++j) {
            int row = w * 8 + j;
            const u16* src = hin + (size_t)(r0 + row) * HH + ((lane ^ (row & 7)) * 8);
            g2l16c(src,       &Abuf[0][row][0]);
            g2l16c(src + 512, &Abuf[1][row][0]);
        }
        // ---- xg prefetch (plain cached; consumed at cell update) ----
        u32x2 xv[4];
        {
            const u16* xp = xg + ((size_t)t * ROWS + r0 + urow) * G4 + j0 + jj4;
            #pragma unroll
            for (int g = 0; g < 4; ++g)
                asm volatile("global_load_dwordx2 %0, %1, off"
                             : "=v"(xv[g]) : "v"(xp + g * HH));
        }

        f32x4 acc[4][4] = {};

        // ---- wait A (xg still in flight), compute both halves ----
        asm volatile("s_waitcnt vmcnt(4)" ::: "memory");
        __builtin_amdgcn_sched_barrier(0);
        __builtin_amdgcn_s_barrier();
        __builtin_amdgcn_sched_barrier(0);
        #pragma unroll
        for (int half = 0; half < 2; ++half) {
            #pragma unroll
            for (int z4 = 0; z4 < 4; ++z4) {
                const int kcl = q * 4 + z4;
                short8 a[4];
                #pragma unroll
                for (int rt = 0; rt < 4; ++rt) {
                    int row = rt * 16 + l15;
                    int c16 = kcl * 4 + l4;
                    a[rt] = *(const short8*)((const char*)&Abuf[half][0][0] +
                             row * 1024 + ((c16 ^ (l15 & 7)) << 4));
                }
                #pragma unroll
                for (int rt = 0; rt < 4; ++rt)
                    #pragma unroll
                    for (int nt = 0; nt < 4; ++nt)
                        acc[rt][nt] = mfma16(a[rt], breg[nt][half * 4 + z4], acc[rt][nt]);
            }
        }
        asm volatile("s_waitcnt lgkmcnt(0)" ::: "memory");
        __builtin_amdgcn_s_barrier();                 // Abuf dead -> G overlay ok
        __builtin_amdgcn_sched_barrier(0);

        // ---- K-combine in G (overlaid): q0/q1 store, q2/q3 add ----
        if (q < 2) {
            #pragma unroll
            for (int rt = 0; rt < 4; ++rt)
                #pragma unroll
                for (int nt = 0; nt < 4; ++nt) {
                    int col = colt * 64 + nt * 16 + l15;
                    int rowb = rt * 16 + l4 * 4;
                    #pragma unroll
                    for (int e = 0; e < 4; ++e)
                        G[((size_t)q * 64 + rowb + e) * 132 + col] = acc[rt][nt][e];
                }
        }
        asm volatile("s_waitcnt lgkmcnt(0)" ::: "memory");
        __builtin_amdgcn_s_barrier();
        __builtin_amdgcn_sched_barrier(0);
        if (q >= 2) {
            #pragma unroll
            for (int rt = 0; rt < 4; ++rt)
                #pragma unroll
                for (int nt = 0; nt < 4; ++nt) {
                    int col = colt * 64 + nt * 16 + l15;
                    int rowb = rt * 16 + l4 * 4;
                    #pragma unroll
                    for (int e = 0; e < 4; ++e)
                        G[((size_t)(q - 2) * 64 + rowb + e) * 132 + col] += acc[rt][nt][e];
                }
        }
        asm volatile("s_waitcnt lgkmcnt(0)" ::: "memory");
        __builtin_amdgcn_s_barrier();
        __builtin_amdgcn_sched_barrier(0);

        // ---- cell update: 4 cells/thread (fast exp2 math); coherent store --
        asm volatile("s_waitcnt vmcnt(0)" ::: "memory");   // xg arrived
        float gv[4][4];
        #pragma unroll
        for (int g = 0; g < 4; ++g) {
            const float* Gr0 = &G[((size_t)0 * 64 + urow) * 132 + g * 32 + jj4];
            const float* Gr1 = &G[((size_t)1 * 64 + urow) * 132 + g * 32 + jj4];
            f32x4 a0 = *(const f32x4*)Gr0;
            f32x4 a1 = *(const f32x4*)Gr1;
            gv[g][0] = a0.x + a1.x + b2f((u16)(xv[g].x & 0xffffu));
            gv[g][1] = a0.y + a1.y + b2f((u16)(xv[g].x >> 16));
            gv[g][2] = a0.z + a1.z + b2f((u16)(xv[g].y & 0xffffu));
            gv[g][3] = a0.w + a1.w + b2f((u16)(xv[g].y >> 16));
        }
        u16 hp[4];
        #pragma unroll
        for (int e = 0; e < 4; ++e) {
            float ii = sigf(gv[0][e]);
            float ff = sigf(gv[1][e]);
            float gg = tanhf_fast(gv[2][e]);
            float oo = sigf(gv[3][e]);
            cst[e] = ff * cst[e] + ii * gg;
            hp[e] = f2b(oo * tanhf_fast(cst[e]));
        }
        u32x2 hw;
        hw.x = (u32)hp[0] | ((u32)hp[1] << 16);
        hw.y = (u32)hp[2] | ((u32)hp[3] << 16);
        {
            u16* hpt = hout + (size_t)(r0 + urow) * HH + j0 + jj4;
            asm volatile("global_store_dwordx2 %0, %1, off sc0 sc1"
                         :: "v"(hpt), "v"(hw) : "memory");
        }

        // ---- flat padded arrival-flag barrier (per 32-block chain) ----
        if (t < TT - 1) {
            asm volatile("s_waitcnt vmcnt(0)" ::: "memory");  // h stores acked
            __builtin_amdgcn_s_barrier();                     // all waves drained
            __builtin_amdgcn_sched_barrier(0);
            const u32 target = (u32)(t + 1);
            if (tid == 0)                                     // arrival: own 128B line
                asm volatile("global_store_dword %0, %1, off sc0 sc1"
                             :: "v"(cb + cg * 32), "v"(target) : "memory");
            if (w == 0) {
                const u32* fp = cb + (lane & 31) * 32;        // 32 padded lines
                int spins = 0;
                while (true) {
                    u32 v;
                    asm volatile("global_load_dword %0, %1, off sc0 sc1"
                                 : "=v"(v) : "v"(fp));
                    asm volatile("s_waitcnt vmcnt(0)" ::: "memory");
                    if (__all(v >= target)) break;
                    __builtin_amdgcn_s_sleep(1);
                    if (++spins > 2000000) break;   // safety bailout
                }
            }
            __builtin_amdgcn_s_barrier();
            __builtin_amdgcn_sched_barrier(0);
        }
    }
}

// ---------------- round-3 fallback: fused per-step kernel ----------------
template<int MODE>
__global__ __launch_bounds__(256) void step_fused(
    const int* __restrict__ ctx, const int* __restrict__ rsp,
    const u16* __restrict__ embb, const u16* __restrict__ Wihb,
    const u16* __restrict__ Whhb, const u16* __restrict__ xg,
    const float* __restrict__ bih, const float* __restrict__ bhh,
    const u16* __restrict__ hin, u16* __restrict__ hout,
    float* __restrict__ c_ws, int t)
{
    __shared__ __align__(16) u16 As[2][64][64];
    __shared__ __align__(16) u16 Ws[2][32][64];
    __shared__ float gs[64][32];
    __shared__ int toks[64];

    const int tid = threadIdx.x;
    const int cg = blockIdx.x & 127, rg = blockIdx.x >> 7;
    const int r0 = rg * 64, j0 = cg * 8;

    if (MODE == 1) {
        if (tid < 64) {
            int r = r0 + tid;
            toks[tid] = (r < BB) ? ctx[r * TT + t] : rsp[(r - BB) * TT + t];
        }
        __syncthreads();
    }

    const int arow0 = tid >> 3, c16a = tid & 7;
    const int arow1 = arow0 + 32;
    const int acol0 = ((c16a ^ (arow0 & 7)) * 8);
    const int acol1 = ((c16a ^ (arow1 & 7)) * 8);
    const u16* hA0 = hin + (size_t)(r0 + arow0) * HH + acol0;
    const u16* hA1 = hin + (size_t)(r0 + arow1) * HH + acol1;
    const u16* eA0 = nullptr; const u16* eA1 = nullptr;
    if (MODE == 1) {
        eA0 = embb + (size_t)toks[arow0] * EE + acol0;
        eA1 = embb + (size_t)toks[arow1] * EE + acol1;
    }
    const int nn = tid >> 3, c16b = tid & 7;
    const int bcol = ((c16b ^ (nn & 7)) * 8);
    const int wrow = (nn >> 3) * HH + j0 + (nn & 7);
    const u16* wHh = Whhb + (size_t)wrow * HH + bcol;
    const u16* wIh = (MODE == 1) ? (Wihb + (size_t)wrow * EE + bcol) : nullptr;

    const int NK = (MODE == 1) ? 24 : 16;

    auto stage = [&](int bs, int it) {
        int kk = it * 64;
        const u16 *s0, *s1, *sw;
        if (MODE == 1 && kk < EE) {
            s0 = eA0 + kk; s1 = eA1 + kk; sw = wIh + kk;
        } else {
            int khh = (MODE == 1) ? kk - EE : kk;
            s0 = hA0 + khh; s1 = hA1 + khh; sw = wHh + khh;
        }
        g2l16(s0, (char*)&As[bs][0][0] + tid * 16);
        g2l16(s1, (char*)&As[bs][0][0] + (tid + 256) * 16);
        g2l16(sw, (char*)&Ws[bs][0][0] + tid * 16);
    };

    const int lane = tid & 63, wave = tid >> 6;
    const int wr = wave * 16;
    const int l15 = lane & 15, l4 = lane >> 4;
    f32x4 acc[2] = {};

    stage(0, 0);
    for (int it = 0; it < NK; ++it) {
        __syncthreads();
        if (it + 1 < NK) stage((it + 1) & 1, it + 1);
        const int b = it & 1;
        #pragma unroll
        for (int ks = 0; ks < 2; ++ks) {
            int c16 = ks * 4 + l4;
            int R = wr + l15;
            short8 a = *(const short8*)((const char*)&As[b][0][0] + R * 128 + ((c16 ^ (R & 7)) << 4));
            #pragma unroll
            for (int nf = 0; nf < 2; ++nf) {
                int Nn = nf * 16 + l15;
                short8 w = *(const short8*)((const char*)&Ws[b][0][0] + Nn * 128 + ((c16 ^ (Nn & 7)) << 4));
                acc[nf] = mfma16(a, w, acc[nf]);
            }
        }
    }
    __syncthreads();
    #pragma unroll
    for (int nf = 0; nf < 2; ++nf)
        #pragma unroll
        for (int q = 0; q < 4; ++q)
            gs[wr + l4 * 4 + q][nf * 16 + l15] = acc[nf][q];
    __syncthreads();

    const int e = tid * 2;
    const int row = e >> 3, jj = e & 7;
    const int rglob = r0 + row;
    float g0[4], g1[4];
    #pragma unroll
    for (int g = 0; g < 4; ++g) { g0[g] = gs[row][g * 8 + jj]; g1[g] = gs[row][g * 8 + jj + 1]; }
    if (MODE == 2) {
        const u16* xp = xg + ((size_t)t * ROWS + rglob) * G4 + j0 + jj;
        #pragma unroll
        for (int g = 0; g < 4; ++g) { g0[g] += b2f(xp[g * HH]); g1[g] += b2f(xp[g * HH + 1]); }
    } else {
        #pragma unroll
        for (int g = 0; g < 4; ++g) {
            int n = g * HH + j0 + jj;
            g0[g] += bih[n] + bhh[n];
            g1[g] += bih[n + 1] + bhh[n + 1];
        }
    }
    size_t cidx = ((size_t)blockIdx.x * 64 + row) * 8 + jj;
    float c0 = c_ws[cidx], c1 = c_ws[cidx + 1];
    float i0 = 1.f / (1.f + expf(-g0[0])), i1 = 1.f / (1.f + expf(-g1[0]));
    float f0 = 1.f / (1.f + expf(-g0[1])), f1 = 1.f / (1.f + expf(-g1[1]));
    float t0 = tanhf(g0[2]),               t1 = tanhf(g1[2]);
    float o0 = 1.f / (1.f + expf(-g0[3])), o1 = 1.f / (1.f + expf(-g1[3]));
    float cn0 = f0 * c0 + i0 * t0;
    float cn1 = f1 * c1 + i1 * t1;
    c_ws[cidx] = cn0; c_ws[cidx + 1] = cn1;
    float h0 = o0 * tanhf(cn0), h1 = o1 * tanhf(cn1);
    unsigned hpk = (unsigned)f2b(h0) | ((unsigned)f2b(h1) << 16);
    *(unsigned*)(hout + (size_t)rglob * HH + j0 + jj) = hpk;
}

// ---------------- mode-0 fallback ----------------
__global__ __launch_bounds__(256) void step_gemm_f32(
    const int* __restrict__ ctx, const int* __restrict__ rsp,
    const float* __restrict__ emb, const float* __restrict__ Wih, const float* __restrict__ Whh,
    const u16* __restrict__ hb, float* __restrict__ gates, int t)
{
    __shared__ __align__(16) u16 As[64][32];
    __shared__ __align__(16) u16 Ws[64][32];
    __shared__ int toks[64];
    const int tid = threadIdx.x;
    const int n0 = blockIdx.x * 64;
    const int r0 = blockIdx.y * 64;
    const int part = blockIdx.z;
    if (tid < 64) {
        int r = r0 + tid;
        toks[tid] = (r < BB) ? ctx[r * TT + t] : rsp[(r - BB) * TT + t];
    }
    __syncthreads();
    const int lane = tid & 63, wave = tid >> 6;
    const int wr = (wave >> 1) * 32, wc = (wave & 1) * 32;
    const int l15 = lane & 15, l4 = lane >> 4;
    f32x4 acc[2][2] = {};
    const int kstart = part * 768;
    const int srow = tid >> 2;
    const int sseg = (tid & 3) * 8;
    for (int it = 0; it < 24; ++it) {
        const int kg = kstart + it * 32;
        const int kk = kg + sseg;
        if (kg < EE) {
            const float* s = emb + (size_t)toks[srow] * EE + kk;
            #pragma unroll
            for (int q = 0; q < 8; ++q) As[srow][sseg + q] = f2b(s[q]);
            const float* sw = Wih + (size_t)(n0 + srow) * EE + kk;
            #pragma unroll
            for (int q = 0; q < 8; ++q) Ws[srow][sseg + q] = f2b(sw[q]);
        } else {
            *(short8*)&As[srow][sseg] = *(const short8*)(hb + (size_t)(r0 + srow) * HH + (kk - EE));
            const float* sw = Whh + (size_t)(n0 + srow) * HH + (kk - EE);
            #pragma unroll
            for (int q = 0; q < 8; ++q) Ws[srow][sseg + q] = f2b(sw[q]);
        }
        __syncthreads();
        #pragma unroll
        for (int mf = 0; mf < 2; ++mf)
            #pragma unroll
            for (int nf = 0; nf < 2; ++nf)
                acc[mf][nf] = mfma16(*(const short8*)&As[wr + mf * 16 + l15][l4 * 8],
                                     *(const short8*)&Ws[wc + nf * 16 + l15][l4 * 8], acc[mf][nf]);
        __syncthreads();
    }
    float* gp = gates + (size_t)part * ROWS * G4;
    #pragma unroll
    for (int mf = 0; mf < 2; ++mf)
        #pragma unroll
        for (int nf = 0; nf < 2; ++nf)
            #pragma unroll
            for (int q = 0; q < 4; ++q) {
                int r = r0 + wr + mf * 16 + l4 * 4 + q;
                int n = n0 + wc + nf * 16 + l15;
                gp[(size_t)r * G4 + n] = acc[mf][nf][q];
            }
}

__global__ __launch_bounds__(256) void lstm_update0(
    const float* __restrict__ gates, const float* __restrict__ bih, const float* __restrict__ bhh,
    u16* __restrict__ hb, float* __restrict__ c)
{
    int idx = blockIdx.x * 256 + threadIdx.x;
    int r = idx >> 8;
    int jj = (idx & 255) * 4;
    const float* gp0 = gates + (size_t)r * G4;
    const float* gp1 = gates + (size_t)(ROWS + r) * G4;
    float gate[4][4];
    #pragma unroll
    for (int g = 0; g < 4; ++g) {
        int n = g * HH + jj;
        f32x4 a = *(const f32x4*)(gp0 + n);
        f32x4 b = *(const f32x4*)(gp1 + n);
        #pragma unroll
        for (int q = 0; q < 4; ++q) gate[g][q] = a[q] + b[q] + bih[n + q] + bhh[n + q];
    }
    int cidx = r * HH + jj;
    f32x4 cv = *(const f32x4*)(c + cidx);
    f32x4 cn; short4v hn;
    #pragma unroll
    for (int q = 0; q < 4; ++q) {
        float si = 1.f / (1.f + expf(-gate[0][q]));
        float sf = 1.f / (1.f + expf(-gate[1][q]));
        float tg = tanhf(gate[2][q]);
        float so = 1.f / (1.f + expf(-gate[3][q]));
        float cval = sf * cv[q] + si * tg;
        cn[q] = cval;
        ((short*)&hn)[q] = (short)f2b(so * tanhf(cval));
    }
    *(f32x4*)(c + cidx) = cn;
    *(short4v*)(hb + cidx) = hn;
}

// ---------------- bilinear head ----------------
__global__ __launch_bounds__(256) void bilinear(
    const u16* __restrict__ hb, const float* __restrict__ M, float* __restrict__ out)
{
    int b = blockIdx.x;
    __shared__ float chs[HH];
    __shared__ float red[256];
    const u16* ch = hb + (size_t)b * HH;
    const u16* rh = hb + (size_t)(BB + b) * HH;
    for (int i = threadIdx.x; i < HH; i += 256) chs[i] = b2f(ch[i]);
    __syncthreads();
    float vj[4] = {0.f, 0.f, 0.f, 0.f};
    for (int i = 0; i < HH; ++i) {
        float chi = chs[i];
        const float* Mr = M + (size_t)i * HH;
        #pragma unroll
        for (int q = 0; q < 4; ++q) vj[q] += chi * Mr[threadIdx.x + q * 256];
    }
    float acc = 0.f;
    #pragma unroll
    for (int q = 0; q < 4; ++q) acc += vj[q] * b2f(rh[threadIdx.x + q * 256]);
    red[threadIdx.x] = acc;
    __syncthreads();
    for (int s = 128; s > 0; s >>= 1) {
        if (threadIdx.x < s) red[threadIdx.x] += red[threadIdx.x + s];
        __syncthreads();
    }
    if (threadIdx.x == 0) out[b] = 1.0f / (1.0f + expf(-red[0]));
}

extern "C" void kernel_launch(void* const* d_in, const int* in_sizes, int n_in,
                              void* d_out, int out_size, void* d_ws, size_t ws_size,
                              hipStream_t stream) {
    const int*   ctx = (const int*)d_in[0];
    const int*   rsp = (const int*)d_in[1];
    const float* emb = (const float*)d_in[2];
    const float* Wih = (const float*)d_in[3];
    const float* Whh = (const float*)d_in[4];
    const float* bih = (const float*)d_in[5];
    const float* bhh = (const float*)d_in[6];
    const float* M   = (const float*)d_in[7];
    float* out = (float*)d_out;

    // workspace layout
    char* w = (char*)d_ws;
    u16*   hbuf  = (u16*)w;   w += (size_t)2 * ROWS * HH * 2;      // 512 KB
    float* c_ws  = (float*)w; w += (size_t)ROWS * HH * 4;          // 512 KB
    float* gates = (float*)w; w += (size_t)2 * ROWS * G4 * 4;      // 4 MB (mode 0)
    u16*   embb  = (u16*)w;   w += (size_t)32000 * EE * 2;         // 31.25 MB
    u16*   Wihb  = (u16*)w;   w += (size_t)G4 * EE * 2;            // 4 MB
    u16*   Whhb  = (u16*)w;   w += (size_t)G4 * HH * 2;            // 8 MB
    u32*   barr  = (u32*)w;   w += 16384;                          // padded barrier
    size_t conv_need = (size_t)(w - (char*)d_ws);
    u16*   xg    = (u16*)w;   w += (size_t)TT * ROWS * G4 * 2;     // 160 MB
    size_t xpre_need = (size_t)(w - (char*)d_ws);

    int mode = (ws_size >= xpre_need) ? 2 : (ws_size >= conv_need) ? 1 : 0;

    hipMemsetAsync(hbuf, 0, (size_t)2 * ROWS * HH * 2, stream);

    if (mode >= 1) {
        cvt_kernel<<<16000, 256, 0, stream>>>(emb, embb, 32000 * EE / 4);
        cvt_kernel<<<2048,  256, 0, stream>>>(Wih, Wihb, G4 * EE / 4);
        cvt_kernel<<<4096,  256, 0, stream>>>(Whh, Whhb, G4 * HH / 4);
    }

    if (mode == 2) {
        hipMemsetAsync(barr, 0, 16384, stream);
        pre_gemm2<<<dim3(G4 / 128, TT), 256, 0, stream>>>(ctx, rsp, embb, Wihb, bih, bhh, xg);
        lstm_persist7<<<NBLK, 512, 0, stream>>>(Whhb, xg, hbuf, barr);
        bilinear<<<BB, 256, 0, stream>>>(hbuf, M, out);   // final h in buffer 0
    } else if (mode == 1) {
        hipMemsetAsync(c_ws, 0, (size_t)ROWS * HH * 4, stream);
        for (int t = 0; t < TT; ++t) {
            const u16* hin = hbuf + (size_t)(t & 1) * ROWS * HH;
            u16* hout      = hbuf + (size_t)((t + 1) & 1) * ROWS * HH;
            step_fused<1><<<256, 256, 0, stream>>>(ctx, rsp, embb, Wihb, Whhb, xg,
                                                   bih, bhh, hin, hout, c_ws, t);
        }
        bilinear<<<BB, 256, 0, stream>>>(hbuf, M, out);
    } else {
        hipMemsetAsync(c_ws, 0, (size_t)ROWS * HH * 4, stream);
        u16* hb = hbuf;
        dim3 sg(G4 / 64, ROWS / 64, 2);
        for (int t = 0; t < TT; ++t) {
            step_gemm_f32<<<sg, 256, 0, stream>>>(ctx, rsp, emb, Wih, Whh, hb, gates, t);
            lstm_update0<<<128, 256, 0, stream>>>(gates, bih, bhh, hb, c_ws);
        }
        bilinear<<<BB, 256, 0, stream>>>(hb, M, out);
    }
}